// Round 1
// baseline (1210.952 us; speedup 1.0000x reference)
//
#include <hip/hip_runtime.h>
#include <math.h>

#define NF 65536
#define NE 1024
#define ED 64
#define KBOT 32768
#define HBINS 8192
#define CAPB 2048
#define CAPT 1024

static const long long OFF_LOSS   = 0;
static const long long OFF_LOSS1  = 1;
static const long long OFF_LOSS2  = 2;
static const long long OFF_ZQST   = 3;
static const long long OFF_ZOUT   = 3LL + 4194304LL;       // 4194307
static const long long OFF_PERP   = 3LL + 8388608LL;       // 8388611
static const long long OFF_MINENC = 8388612LL;             // 16B aligned (x4)
static const long long OFF_IDX    = 75497476LL;            // 16B aligned (x4)
static const long long OFF_NEP    = 75563012LL;
static const long long OFF_NEMB   = 75564036LL;

__device__ __forceinline__ unsigned ordf(float v){
  unsigned u = __float_as_uint(v);
  return (u & 0x80000000u) ? ~u : (u | 0x80000000u);
}

// Replicates np.linalg.norm(x) for a 64-elem row: squares rounded to fp32,
// pairwise_sum with 8 accumulators + combine tree, sqrt, max(.,1e-12).
__device__ __forceinline__ float np_l2norm_row(const float* __restrict__ x){
  float r[8];
  #pragma unroll
  for (int j=0;j<8;j++){ float t=x[j]; r[j]=__fmul_rn(t,t); }
  #pragma unroll
  for (int b=1;b<8;b++){
    #pragma unroll
    for (int j=0;j<8;j++){ float t=x[b*8+j]; r[j]=__fadd_rn(r[j], __fmul_rn(t,t)); }
  }
  float s = __fadd_rn(__fadd_rn(__fadd_rn(r[0],r[1]),__fadd_rn(r[2],r[3])),
                      __fadd_rn(__fadd_rn(r[4],r[5]),__fadd_rn(r[6],r[7])));
  float nr = __fsqrt_rn(s);
  return fmaxf(nr, 1e-12f);
}

__global__ void norm_z_kernel(const float* __restrict__ z, float* __restrict__ zn){
  int f = blockIdx.x*blockDim.x + threadIdx.x;    // < 65536
  const float* x = z + (size_t)f*ED;
  float nr = np_l2norm_row(x);
  float* o = zn + (size_t)f*ED;
  #pragma unroll
  for (int i=0;i<ED;i++) o[i] = __fdiv_rn(x[i], nr);
}

__global__ void norm_emb_kernel(const float* __restrict__ emb, float* __restrict__ cn){
  int n = blockIdx.x*blockDim.x + threadIdx.x;    // < 1024
  const float* x = emb + (size_t)n*ED;
  float nr = np_l2norm_row(x);
  float* o = cn + (size_t)n*ED;
  #pragma unroll
  for (int i=0;i<ED;i++) o[i] = __fdiv_rn(x[i], nr);
}

// d = zn @ cn^T   (65536 x 1024, K=64), stored TRANSPOSED: dT[c][row].
// Also computes per-row argmax (first occurrence) and histogram of idx.
__global__ __launch_bounds__(256) void gemm_kernel(const float* __restrict__ zn,
      const float* __restrict__ cn, float* __restrict__ dT,
      int* __restrict__ idxw, int* __restrict__ counts){
  __shared__ float zsh[16*64];
  __shared__ unsigned long long redk[4][16];
  const int tid = threadIdx.x;
  const int r0  = blockIdx.x * 16;
  for (int i=tid;i<1024;i+=256) zsh[i] = zn[(size_t)r0*ED + i];
  __syncthreads();
  const int c0 = tid*4;
  float acc[64];
  #pragma unroll
  for (int i=0;i<64;i++) acc[i]=0.0f;
  const float4* zsh4 = (const float4*)zsh;
  #pragma unroll
  for (int k4=0;k4<16;k4++){
    float4 w0 = *(const float4*)(cn + (size_t)(c0+0)*ED + k4*4);
    float4 w1 = *(const float4*)(cn + (size_t)(c0+1)*ED + k4*4);
    float4 w2 = *(const float4*)(cn + (size_t)(c0+2)*ED + k4*4);
    float4 w3 = *(const float4*)(cn + (size_t)(c0+3)*ED + k4*4);
    #pragma unroll
    for (int r=0;r<16;r++){
      float4 zr = zsh4[r*16 + k4];
      float* a0=&acc[r*4+0]; float* a1=&acc[r*4+1]; float* a2=&acc[r*4+2]; float* a3=&acc[r*4+3];
      *a0=fmaf(zr.x,w0.x,*a0); *a0=fmaf(zr.y,w0.y,*a0); *a0=fmaf(zr.z,w0.z,*a0); *a0=fmaf(zr.w,w0.w,*a0);
      *a1=fmaf(zr.x,w1.x,*a1); *a1=fmaf(zr.y,w1.y,*a1); *a1=fmaf(zr.z,w1.z,*a1); *a1=fmaf(zr.w,w1.w,*a1);
      *a2=fmaf(zr.x,w2.x,*a2); *a2=fmaf(zr.y,w2.y,*a2); *a2=fmaf(zr.z,w2.z,*a2); *a2=fmaf(zr.w,w2.w,*a2);
      *a3=fmaf(zr.x,w3.x,*a3); *a3=fmaf(zr.y,w3.y,*a3); *a3=fmaf(zr.z,w3.z,*a3); *a3=fmaf(zr.w,w3.w,*a3);
    }
  }
  #pragma unroll
  for (int j=0;j<4;j++){
    float4* dst = (float4*)(dT + (size_t)(c0+j)*NF + r0);
    dst[0]=make_float4(acc[0*4+j],acc[1*4+j],acc[2*4+j],acc[3*4+j]);
    dst[1]=make_float4(acc[4*4+j],acc[5*4+j],acc[6*4+j],acc[7*4+j]);
    dst[2]=make_float4(acc[8*4+j],acc[9*4+j],acc[10*4+j],acc[11*4+j]);
    dst[3]=make_float4(acc[12*4+j],acc[13*4+j],acc[14*4+j],acc[15*4+j]);
  }
  #pragma unroll
  for (int r=0;r<16;r++){
    float bv = acc[r*4]; int bc=0;
    #pragma unroll
    for (int j=1;j<4;j++) if (acc[r*4+j] > bv){ bv=acc[r*4+j]; bc=j; }
    unsigned long long key = ((unsigned long long)ordf(bv)<<32) |
                             (unsigned long long)(0xFFFFFFFFu - (unsigned)(c0+bc));
    #pragma unroll
    for (int off=32;off;off>>=1){
      unsigned long long o = __shfl_down(key, off);
      if (o > key) key = o;
    }
    if ((tid&63)==0) redk[tid>>6][r] = key;
  }
  __syncthreads();
  if (tid < 16){
    unsigned long long K = redk[0][tid];
    #pragma unroll
    for (int w=1;w<4;w++) if (redk[w][tid] > K) K = redk[w][tid];
    int col = (int)(0xFFFFFFFFu - (unsigned)(K & 0xFFFFFFFFull));
    idxw[r0 + tid] = col;
    atomicAdd(&counts[col], 1);
  }
}

__device__ void bitonic_sort(float* buf, int N, int tid){
  for (int k=2;k<=N;k<<=1){
    for (int j=k>>1;j>0;j>>=1){
      for (int t=tid;t<N;t+=256){
        int ixj = t ^ j;
        if (ixj > t){
          float a = buf[t], b = buf[ixj];
          bool up = ((t & k) == 0);
          bool sw = up ? (a > b) : (a < b);
          if (sw){ buf[t]=b; buf[ixj]=a; }
        }
      }
      __syncthreads();
    }
  }
}

// One block per codebook column: col max+first-argmax (anchor), exact mean of
// top-64, exact sum of exp over the bottom 32768 values -> contra_n = log1p(S).
__global__ __launch_bounds__(256) void colstats_kernel(const float* __restrict__ dT,
        int* __restrict__ anchor, double* __restrict__ accs){
  __shared__ unsigned hist[HBINS];
  __shared__ float bufB[CAPB];
  __shared__ float bufT[CAPT];
  __shared__ unsigned csum_sh[256];
  __shared__ unsigned pre_sh[256];
  __shared__ float redf[256];
  __shared__ unsigned long long redk[4];
  __shared__ float s_m0f;
  __shared__ int s_anch;
  __shared__ int s_binB, s_cbelow, s_binT;
  __shared__ int s_cntB, s_cntT;

  const int tid = threadIdx.x;
  const int n = blockIdx.x;
  const float* __restrict__ p = dT + (size_t)n*NF;

  for (int i=tid;i<HBINS;i+=256) hist[i]=0u;
  if (tid==0){ s_cntB=0; s_cntT=0; }
  __syncthreads();

  unsigned long long bk=0ull;
  for (int i=tid;i<NF;i+=256){
    float v = p[i];
    unsigned long long key = ((unsigned long long)ordf(v)<<32) |
                             (unsigned long long)(~(unsigned)i);
    if (key>bk) bk=key;
    int b = (int)((v+1.0f)*4096.0f);
    b = b<0?0:(b>HBINS-1?HBINS-1:b);
    atomicAdd(&hist[b],1u);
  }
  #pragma unroll
  for (int off=32;off;off>>=1){
    unsigned long long o=__shfl_down(bk,off);
    if (o>bk) bk=o;
  }
  if ((tid&63)==0) redk[tid>>6]=bk;
  __syncthreads();
  if (tid==0){
    unsigned long long K=redk[0];
    for (int w=1;w<4;w++) if (redk[w]>K) K=redk[w];
    unsigned ou=(unsigned)(K>>32);
    unsigned u = (ou&0x80000000u)?(ou^0x80000000u):~ou;
    s_m0f = __uint_as_float(u);
    s_anch = (int)(~(unsigned)(K&0xFFFFFFFFull));
  }
  unsigned cs=0;
  {
    const int b0=tid*32;
    #pragma unroll
    for (int i2=0;i2<32;i2++) cs+=hist[b0+i2];
    csum_sh[tid]=cs;
  }
  __syncthreads();
  if (tid==0){
    unsigned run=0;
    for (int t=0;t<256;t++){ pre_sh[t]=run; run+=csum_sh[t]; }
  }
  __syncthreads();
  {
    const unsigned pre=pre_sh[tid];
    const int b0=tid*32;
    if (pre < (unsigned)KBOT && pre+cs >= (unsigned)KBOT){
      unsigned run=pre;
      for (int i2=0;i2<32;i2++){
        unsigned c=hist[b0+i2];
        if (run<(unsigned)KBOT && run+c>=(unsigned)KBOT){ s_binB=b0+i2; s_cbelow=(int)run; }
        run+=c;
      }
    }
    unsigned Rt = (unsigned)NF - pre;
    unsigned Rn = Rt - cs;
    if (Rt>=64u && Rn<64u){
      unsigned R=Rt;
      for (int i2=0;i2<32;i2++){
        unsigned c=hist[b0+i2];
        unsigned R2=R-c;
        if (R>=64u && R2<64u){ s_binT=b0+i2; }
        R=R2;
      }
    }
  }
  __syncthreads();

  const int binB=s_binB, binT=s_binT;
  const float m0=s_m0f;
  const float LINV = 1.0f/0.07f;
  float es=0.0f;
  for (int i=tid;i<NF;i+=256){
    float v=p[i];
    int b=(int)((v+1.0f)*4096.0f);
    b=b<0?0:(b>HBINS-1?HBINS-1:b);
    if (b<binB) es += expf((v-m0)*LINV);
    if (b==binB){ int pos=atomicAdd(&s_cntB,1); if (pos<CAPB) bufB[pos]=v; }
    if (b>=binT){ int pos=atomicAdd(&s_cntT,1); if (pos<CAPT) bufT[pos]=v; }
  }
  redf[tid]=es;
  __syncthreads();
  for (int off=128;off;off>>=1){
    if (tid<off) redf[tid]+=redf[tid+off];
    __syncthreads();
  }
  const float E_below = redf[0];
  const int cntB = (s_cntB<CAPB)?s_cntB:CAPB;
  const int cntT = (s_cntT<CAPT)?s_cntT:CAPT;
  __syncthreads();
  for (int i=cntB+tid;i<CAPB;i+=256) bufB[i]=__uint_as_float(0x7f800000u);
  for (int i=cntT+tid;i<CAPT;i+=256) bufT[i]=__uint_as_float(0xff800000u);
  __syncthreads();
  bitonic_sort(bufB, CAPB, tid);
  bitonic_sort(bufT, CAPT, tid);
  int m = KBOT - s_cbelow; if (m>cntB) m=cntB;
  float es2=0.0f;
  for (int i=tid;i<m;i+=256) es2 += expf((bufB[i]-m0)*LINV);
  redf[tid]=es2;
  __syncthreads();
  for (int off=128;off;off>>=1){ if (tid<off) redf[tid]+=redf[tid+off]; __syncthreads(); }
  const float E_bin = redf[0];
  __syncthreads();
  redf[tid] = (tid<64) ? bufT[CAPT-64+tid] : 0.0f;
  __syncthreads();
  for (int off=128;off;off>>=1){ if (tid<off) redf[tid]+=redf[tid+off]; __syncthreads(); }
  if (tid==0){
    float topSum = redf[0];
    float dis_pos = topSum*(1.0f/64.0f);
    float S = (E_below+E_bin)*expf((m0-dis_pos)*LINV);
    atomicAdd(&accs[1], (double)log1pf(S));
    anchor[n] = s_anch;
  }
}

__global__ void scatter_kernel(const int* __restrict__ idxw, float* __restrict__ minenc){
  int f = blockIdx.x*256 + threadIdx.x;
  minenc[(size_t)f*NE + idxw[f]] = 1.0f;
}

__global__ __launch_bounds__(256) void zq_kernel(const float* __restrict__ z,
        const float* __restrict__ emb, const int* __restrict__ idxw,
        float* __restrict__ out, double* __restrict__ lossAcc){
  const int gid = blockIdx.x*256 + threadIdx.x;   // < 1048576 (float4 units)
  const int f = gid >> 4;
  const int e0 = (gid & 15)*4;
  const int c = idxw[f];
  const float4 q = *(const float4*)(emb + (size_t)c*ED + e0);
  const float4 zv = ((const float4*)z)[gid];
  float dx=__fsub_rn(q.x,zv.x), dy=__fsub_rn(q.y,zv.y);
  float dz2=__fsub_rn(q.z,zv.z), dw=__fsub_rn(q.w,zv.w);
  float ox=__fadd_rn(zv.x,dx), oy=__fadd_rn(zv.y,dy);
  float oz=__fadd_rn(zv.z,dz2), ow=__fadd_rn(zv.w,dw);
  size_t base = (size_t)gid*4;
  float* zq = out + OFF_ZQST; float* zo = out + OFF_ZOUT;
  zq[base+0]=ox; zq[base+1]=oy; zq[base+2]=oz; zq[base+3]=ow;
  zo[base+0]=ox; zo[base+1]=oy; zo[base+2]=oz; zo[base+3]=ow;
  if ((gid&15)==0) out[OFF_IDX + f] = (float)c;
  float ls = __fadd_rn(__fadd_rn(__fmul_rn(dx,dx),__fmul_rn(dy,dy)),
                       __fadd_rn(__fmul_rn(dz2,dz2),__fmul_rn(dw,dw)));
  #pragma unroll
  for (int off=32;off;off>>=1) ls += __shfl_down(ls, off);
  __shared__ float rw[4];
  if ((threadIdx.x&63)==0) rw[threadIdx.x>>6]=ls;
  __syncthreads();
  if (threadIdx.x==0) atomicAdd(lossAcc, (double)(((rw[0]+rw[1])+(rw[2]+rw[3]))));
}

__global__ void codebook_kernel(const float* __restrict__ emb, const float* __restrict__ eprob,
     const float* __restrict__ z, const int* __restrict__ counts, const int* __restrict__ anchor,
     float* __restrict__ out, double* __restrict__ perpAcc){
  const int n = blockIdx.x;
  const int e = threadIdx.x;   // 64
  float em = (float)counts[n] * (1.0f/65536.0f);
  float nep = __fadd_rn(__fmul_rn(eprob[n],0.99f), __fmul_rn(em,0.01f));
  if (e==0){
    out[OFF_NEP + n] = nep;
    atomicAdd(perpAcc, (double)__fmul_rn(em, logf(__fadd_rn(em,1e-10f))));
  }
  float t = __fmul_rn(__fmul_rn(nep,1024.0f),10.0f);
  t = __fdiv_rn(-t, 0.01f);
  t = __fsub_rn(t, 0.001f);
  float dec = expf(t);
  float onem = __fsub_rn(1.0f, dec);
  int a = anchor[n];
  float nv = __fadd_rn(__fmul_rn(emb[(size_t)n*ED+e], onem),
                       __fmul_rn(z[(size_t)a*ED+e], dec));
  out[OFF_NEMB + (size_t)n*ED + e] = nv;
}

__global__ void finalize_kernel(const double* __restrict__ accs, float* __restrict__ out){
  if (threadIdx.x==0 && blockIdx.x==0){
    float l1 = (float)(accs[0] / 4194304.0);
    float contra = (float)(accs[1] / 1024.0);
    out[OFF_LOSS1]=l1; out[OFF_LOSS2]=l1;
    float loss = __fadd_rn(__fadd_rn(__fmul_rn(1.0f,l1), __fmul_rn(0.25f,l1)), contra);
    out[OFF_LOSS]=loss;
    out[OFF_PERP]=expf(-(float)accs[2]);
  }
}

extern "C" void kernel_launch(void* const* d_in, const int* in_sizes, int n_in,
                              void* d_out, int out_size, void* d_ws, size_t ws_size,
                              hipStream_t stream){
  (void)in_sizes; (void)n_in; (void)out_size; (void)ws_size;
  const float* z    = (const float*)d_in[0];
  const float* emb  = (const float*)d_in[1];
  const float* eprb = (const float*)d_in[2];
  float* out = (float*)d_out;
  char* ws = (char*)d_ws;
  double* accs = (double*)ws;                 // [0]=lossSum [1]=contraSum [2]=perpSum
  int* counts = (int*)(ws + 64);              // 1024 ints
  int* anchor = (int*)(ws + 8192);            // 1024 ints
  int* idxw   = (int*)(ws + 16384);           // 65536 ints
  float* cn = out + OFF_IDX;                  // scratch: idx region (written later)
  float* zn = out + OFF_ZOUT;                 // scratch: z_output region (written later)
  float* dT = out + OFF_MINENC;               // scratch: min_encodings region (overwritten later)

  hipMemsetAsync(ws, 0, 16384, stream);
  hipLaunchKernelGGL(norm_emb_kernel, dim3(4), dim3(256), 0, stream, emb, cn);
  hipLaunchKernelGGL(norm_z_kernel, dim3(256), dim3(256), 0, stream, z, zn);
  hipLaunchKernelGGL(gemm_kernel, dim3(4096), dim3(256), 0, stream, zn, cn, dT, idxw, counts);
  hipLaunchKernelGGL(colstats_kernel, dim3(1024), dim3(256), 0, stream, dT, anchor, accs);
  hipMemsetAsync(dT, 0, (size_t)67108864*4, stream);
  hipLaunchKernelGGL(scatter_kernel, dim3(256), dim3(256), 0, stream, idxw, dT);
  hipLaunchKernelGGL(zq_kernel, dim3(4096), dim3(256), 0, stream, z, emb, idxw, out, accs);
  hipLaunchKernelGGL(codebook_kernel, dim3(1024), dim3(64), 0, stream, emb, eprb, z, counts, anchor, out, accs+2);
  hipLaunchKernelGGL(finalize_kernel, dim3(1), dim3(1), 0, stream, accs, out);
}

// Round 2
// 815.471 us; speedup vs baseline: 1.4850x; 1.4850x over previous
//
#include <hip/hip_runtime.h>
#include <math.h>

#define NF 65536
#define NE 1024
#define ED 64
#define KBOT 32768
#define RTOP 65472            // NF - 64
#define BINS 2048
#define CAPB 2048
#define CAPT 1024

static const long long OFF_LOSS   = 0;
static const long long OFF_LOSS1  = 1;
static const long long OFF_LOSS2  = 2;
static const long long OFF_ZQST   = 3;
static const long long OFF_ZOUT   = 3LL + 4194304LL;       // 4194307
static const long long OFF_PERP   = 3LL + 8388608LL;       // 8388611
static const long long OFF_MINENC = 8388612LL;             // 16B aligned (x4)
static const long long OFF_IDX    = 75497476LL;            // 16B aligned (x4)
static const long long OFF_NEP    = 75563012LL;
static const long long OFF_NEMB   = 75564036LL;

__device__ __forceinline__ unsigned ordf(float v){
  unsigned u = __float_as_uint(v);
  return (u & 0x80000000u) ? ~u : (u | 0x80000000u);
}

// Replicates np.linalg.norm(x) for a 64-elem row: squares rounded to fp32,
// pairwise_sum with 8 accumulators + combine tree, sqrt, max(.,1e-12).
__device__ __forceinline__ float np_l2norm_row(const float* __restrict__ x){
  float r[8];
  #pragma unroll
  for (int j=0;j<8;j++){ float t=x[j]; r[j]=__fmul_rn(t,t); }
  #pragma unroll
  for (int b=1;b<8;b++){
    #pragma unroll
    for (int j=0;j<8;j++){ float t=x[b*8+j]; r[j]=__fadd_rn(r[j], __fmul_rn(t,t)); }
  }
  float s = __fadd_rn(__fadd_rn(__fadd_rn(r[0],r[1]),__fadd_rn(r[2],r[3])),
                      __fadd_rn(__fadd_rn(r[4],r[5]),__fadd_rn(r[6],r[7])));
  float nr = __fsqrt_rn(s);
  return fmaxf(nr, 1e-12f);
}

__global__ void norm_z_kernel(const float* __restrict__ z, float* __restrict__ zn){
  int f = blockIdx.x*blockDim.x + threadIdx.x;    // < 65536
  const float* x = z + (size_t)f*ED;
  float nr = np_l2norm_row(x);
  float* o = zn + (size_t)f*ED;
  #pragma unroll
  for (int i=0;i<ED;i++) o[i] = __fdiv_rn(x[i], nr);
}

__global__ void norm_emb_kernel(const float* __restrict__ emb, float* __restrict__ cn){
  int n = blockIdx.x*blockDim.x + threadIdx.x;    // < 1024
  const float* x = emb + (size_t)n*ED;
  float nr = np_l2norm_row(x);
  float* o = cn + (size_t)n*ED;
  #pragma unroll
  for (int i=0;i<ED;i++) o[i] = __fdiv_rn(x[i], nr);
}

// d = zn @ cn^T   (65536 x 1024, K=64), stored TRANSPOSED: dT[c][row].
// Also computes per-row argmax (first occurrence) and histogram of idx.
__global__ __launch_bounds__(256) void gemm_kernel(const float* __restrict__ zn,
      const float* __restrict__ cn, float* __restrict__ dT,
      int* __restrict__ idxw, int* __restrict__ counts){
  __shared__ float zsh[16*64];
  __shared__ unsigned long long redk[4][16];
  const int tid = threadIdx.x;
  const int r0  = blockIdx.x * 16;
  for (int i=tid;i<1024;i+=256) zsh[i] = zn[(size_t)r0*ED + i];
  __syncthreads();
  const int c0 = tid*4;
  float acc[64];
  #pragma unroll
  for (int i=0;i<64;i++) acc[i]=0.0f;
  const float4* zsh4 = (const float4*)zsh;
  #pragma unroll
  for (int k4=0;k4<16;k4++){
    float4 w0 = *(const float4*)(cn + (size_t)(c0+0)*ED + k4*4);
    float4 w1 = *(const float4*)(cn + (size_t)(c0+1)*ED + k4*4);
    float4 w2 = *(const float4*)(cn + (size_t)(c0+2)*ED + k4*4);
    float4 w3 = *(const float4*)(cn + (size_t)(c0+3)*ED + k4*4);
    #pragma unroll
    for (int r=0;r<16;r++){
      float4 zr = zsh4[r*16 + k4];
      float* a0=&acc[r*4+0]; float* a1=&acc[r*4+1]; float* a2=&acc[r*4+2]; float* a3=&acc[r*4+3];
      *a0=fmaf(zr.x,w0.x,*a0); *a0=fmaf(zr.y,w0.y,*a0); *a0=fmaf(zr.z,w0.z,*a0); *a0=fmaf(zr.w,w0.w,*a0);
      *a1=fmaf(zr.x,w1.x,*a1); *a1=fmaf(zr.y,w1.y,*a1); *a1=fmaf(zr.z,w1.z,*a1); *a1=fmaf(zr.w,w1.w,*a1);
      *a2=fmaf(zr.x,w2.x,*a2); *a2=fmaf(zr.y,w2.y,*a2); *a2=fmaf(zr.z,w2.z,*a2); *a2=fmaf(zr.w,w2.w,*a2);
      *a3=fmaf(zr.x,w3.x,*a3); *a3=fmaf(zr.y,w3.y,*a3); *a3=fmaf(zr.z,w3.z,*a3); *a3=fmaf(zr.w,w3.w,*a3);
    }
  }
  #pragma unroll
  for (int j=0;j<4;j++){
    float4* dst = (float4*)(dT + (size_t)(c0+j)*NF + r0);
    dst[0]=make_float4(acc[0*4+j],acc[1*4+j],acc[2*4+j],acc[3*4+j]);
    dst[1]=make_float4(acc[4*4+j],acc[5*4+j],acc[6*4+j],acc[7*4+j]);
    dst[2]=make_float4(acc[8*4+j],acc[9*4+j],acc[10*4+j],acc[11*4+j]);
    dst[3]=make_float4(acc[12*4+j],acc[13*4+j],acc[14*4+j],acc[15*4+j]);
  }
  #pragma unroll
  for (int r=0;r<16;r++){
    float bv = acc[r*4]; int bc=0;
    #pragma unroll
    for (int j=1;j<4;j++) if (acc[r*4+j] > bv){ bv=acc[r*4+j]; bc=j; }
    unsigned long long key = ((unsigned long long)ordf(bv)<<32) |
                             (unsigned long long)(0xFFFFFFFFu - (unsigned)(c0+bc));
    #pragma unroll
    for (int off=32;off;off>>=1){
      unsigned long long o = __shfl_down(key, off);
      if (o > key) key = o;
    }
    if ((tid&63)==0) redk[tid>>6][r] = key;
  }
  __syncthreads();
  if (tid < 16){
    unsigned long long K = redk[0][tid];
    #pragma unroll
    for (int w=1;w<4;w++) if (redk[w][tid] > K) K = redk[w][tid];
    int col = (int)(0xFFFFFFFFu - (unsigned)(K & 0xFFFFFFFFull));
    idxw[r0 + tid] = col;
    atomicAdd(&counts[col], 1);
  }
}

__device__ void bitonic_sort(float* buf, int N, int tid, int nthr){
  for (int k=2;k<=N;k<<=1){
    for (int j=k>>1;j>0;j>>=1){
      for (int t=tid;t<N;t+=nthr){
        int ixj = t ^ j;
        if (ixj > t){
          float a = buf[t], b = buf[ixj];
          bool up = ((t & k) == 0);
          bool sw = up ? (a > b) : (a < b);
          if (sw){ buf[t]=b; buf[ixj]=a; }
        }
      }
      __syncthreads();
    }
  }
}

// One block (1024 thr) per codebook column:
//   pass1: 2048-bin histogram + col max/first-argmax
//   parallel scan -> cutoff bins for rank 32768 (binB) and rank NF-64 (binT)
//   pass2: exact exp-sum below binB + gather binB / >=binT candidates
//   small bitonic sorts -> exact bottom-32768 exp-sum and exact top-64 mean
//   then zero-writes its column slice (min_encodings region) -> replaces memset.
__global__ __launch_bounds__(1024) void colstats_kernel(float* __restrict__ dT,
        int* __restrict__ anchor, double* __restrict__ accs){
  __shared__ unsigned hist[BINS];
  __shared__ unsigned scan[1024];
  __shared__ float bufB[CAPB];
  __shared__ float bufT[CAPT];
  __shared__ float redf[1024];
  __shared__ unsigned long long redk[16];
  __shared__ float s_m0f;
  __shared__ int s_anch;
  __shared__ int s_binB, s_cbelow, s_binT;
  __shared__ int s_cntB, s_cntT;

  const int tid = threadIdx.x;
  const int n = blockIdx.x;
  float* __restrict__ p = dT + (size_t)n*NF;

  hist[tid]=0u; hist[tid+1024]=0u;
  if (tid==0){ s_cntB=0; s_cntT=0; }
  __syncthreads();

  // ---- pass 1: histogram + max-key ----
  unsigned long long bk=0ull;
  for (int i=tid;i<NF;i+=1024){
    float v = p[i];
    unsigned long long key = ((unsigned long long)ordf(v)<<32) |
                             (unsigned long long)(~(unsigned)i);
    if (key>bk) bk=key;
    int b = (int)((v+1.0f)*1024.0f);
    b = b<0?0:(b>BINS-1?BINS-1:b);
    atomicAdd(&hist[b],1u);
  }
  #pragma unroll
  for (int off=32;off;off>>=1){
    unsigned long long o=__shfl_down(bk,off);
    if (o>bk) bk=o;
  }
  if ((tid&63)==0) redk[tid>>6]=bk;
  __syncthreads();
  if (tid==0){
    unsigned long long K=redk[0];
    #pragma unroll
    for (int w=1;w<16;w++) if (redk[w]>K) K=redk[w];
    unsigned ou=(unsigned)(K>>32);
    unsigned u = (ou&0x80000000u)?(ou^0x80000000u):~ou;
    s_m0f = __uint_as_float(u);
    s_anch = (int)(~(unsigned)(K&0xFFFFFFFFull));
  }

  // ---- parallel inclusive scan over bin-pairs ----
  const unsigned h0 = hist[2*tid], h1 = hist[2*tid+1];
  const unsigned c2 = h0+h1;
  scan[tid]=c2;
  __syncthreads();
  for (int off=1;off<1024;off<<=1){
    unsigned y = (tid>=off)? scan[tid-off] : 0u;
    __syncthreads();
    scan[tid]+=y;
    __syncthreads();
  }
  {
    const unsigned inc = scan[tid];
    const unsigned pre = inc - c2;
    if (pre < (unsigned)KBOT && pre+h0 >= (unsigned)KBOT){ s_binB=2*tid;   s_cbelow=(int)pre; }
    else if (pre+h0 < (unsigned)KBOT && inc >= (unsigned)KBOT){ s_binB=2*tid+1; s_cbelow=(int)(pre+h0); }
    if (pre <= (unsigned)RTOP && (unsigned)RTOP < pre+h0) s_binT=2*tid;
    else if (pre+h0 <= (unsigned)RTOP && (unsigned)RTOP < inc) s_binT=2*tid+1;
  }
  __syncthreads();

  // ---- pass 2: exp-sum + candidate gather ----
  const int binB=s_binB, binT=s_binT;
  const float m0=s_m0f;
  const float LINV = 1.0f/0.07f;
  float es=0.0f;
  for (int i=tid;i<NF;i+=1024){
    float v=p[i];
    int b=(int)((v+1.0f)*1024.0f);
    b=b<0?0:(b>BINS-1?BINS-1:b);
    if (b<binB) es += expf((v-m0)*LINV);
    if (b==binB){ int pos=atomicAdd(&s_cntB,1); if (pos<CAPB) bufB[pos]=v; }
    if (b>=binT){ int pos=atomicAdd(&s_cntT,1); if (pos<CAPT) bufT[pos]=v; }
  }
  redf[tid]=es;
  __syncthreads();
  for (int off=512;off;off>>=1){
    if (tid<off) redf[tid]+=redf[tid+off];
    __syncthreads();
  }
  const float E_below = redf[0];
  const int cntB = (s_cntB<CAPB)?s_cntB:CAPB;
  const int cntT = (s_cntT<CAPT)?s_cntT:CAPT;
  __syncthreads();
  for (int i=cntB+tid;i<CAPB;i+=1024) bufB[i]=__uint_as_float(0x7f800000u);
  for (int i=cntT+tid;i<CAPT;i+=1024) bufT[i]=__uint_as_float(0xff800000u);
  __syncthreads();
  bitonic_sort(bufB, CAPB, tid, 1024);
  bitonic_sort(bufT, CAPT, tid, 1024);
  int m = KBOT - s_cbelow; if (m>cntB) m=cntB;
  float es2=0.0f;
  for (int i=tid;i<m;i+=1024) es2 += expf((bufB[i]-m0)*LINV);
  redf[tid]=es2;
  __syncthreads();
  for (int off=512;off;off>>=1){ if (tid<off) redf[tid]+=redf[tid+off]; __syncthreads(); }
  const float E_bin = redf[0];
  __syncthreads();
  redf[tid] = (tid<64) ? bufT[CAPT-64+tid] : 0.0f;
  __syncthreads();
  for (int off=512;off;off>>=1){ if (tid<off) redf[tid]+=redf[tid+off]; __syncthreads(); }
  if (tid==0){
    float topSum = redf[0];
    float dis_pos = topSum*(1.0f/64.0f);
    float S = (E_below+E_bin)*expf((m0-dis_pos)*LINV);
    atomicAdd(&accs[1], (double)log1pf(S));
    anchor[n] = s_anch;
  }
  // ---- zero this column slice (becomes min_encodings zeros) ----
  float4 z4 = make_float4(0.f,0.f,0.f,0.f);
  float4* p4 = (float4*)p;
  for (int i=tid;i<NF/4;i+=1024) p4[i]=z4;
}

__global__ void scatter_kernel(const int* __restrict__ idxw, float* __restrict__ minenc){
  int f = blockIdx.x*256 + threadIdx.x;
  minenc[(size_t)f*NE + idxw[f]] = 1.0f;
}

__global__ __launch_bounds__(256) void zq_kernel(const float* __restrict__ z,
        const float* __restrict__ emb, const int* __restrict__ idxw,
        float* __restrict__ out, double* __restrict__ lossAcc){
  const int gid = blockIdx.x*256 + threadIdx.x;   // < 1048576 (float4 units)
  const int f = gid >> 4;
  const int e0 = (gid & 15)*4;
  const int c = idxw[f];
  const float4 q = *(const float4*)(emb + (size_t)c*ED + e0);
  const float4 zv = ((const float4*)z)[gid];
  float dx=__fsub_rn(q.x,zv.x), dy=__fsub_rn(q.y,zv.y);
  float dz2=__fsub_rn(q.z,zv.z), dw=__fsub_rn(q.w,zv.w);
  float ox=__fadd_rn(zv.x,dx), oy=__fadd_rn(zv.y,dy);
  float oz=__fadd_rn(zv.z,dz2), ow=__fadd_rn(zv.w,dw);
  size_t base = (size_t)gid*4;
  float* zq = out + OFF_ZQST; float* zo = out + OFF_ZOUT;
  zq[base+0]=ox; zq[base+1]=oy; zq[base+2]=oz; zq[base+3]=ow;
  zo[base+0]=ox; zo[base+1]=oy; zo[base+2]=oz; zo[base+3]=ow;
  if ((gid&15)==0) out[OFF_IDX + f] = (float)c;
  float ls = __fadd_rn(__fadd_rn(__fmul_rn(dx,dx),__fmul_rn(dy,dy)),
                       __fadd_rn(__fmul_rn(dz2,dz2),__fmul_rn(dw,dw)));
  #pragma unroll
  for (int off=32;off;off>>=1) ls += __shfl_down(ls, off);
  __shared__ float rw[4];
  if ((threadIdx.x&63)==0) rw[threadIdx.x>>6]=ls;
  __syncthreads();
  if (threadIdx.x==0) atomicAdd(lossAcc, (double)(((rw[0]+rw[1])+(rw[2]+rw[3]))));
}

__global__ void codebook_kernel(const float* __restrict__ emb, const float* __restrict__ eprob,
     const float* __restrict__ z, const int* __restrict__ counts, const int* __restrict__ anchor,
     float* __restrict__ out, double* __restrict__ perpAcc){
  const int n = blockIdx.x;
  const int e = threadIdx.x;   // 64
  float em = (float)counts[n] * (1.0f/65536.0f);
  float nep = __fadd_rn(__fmul_rn(eprob[n],0.99f), __fmul_rn(em,0.01f));
  if (e==0){
    out[OFF_NEP + n] = nep;
    atomicAdd(perpAcc, (double)__fmul_rn(em, logf(__fadd_rn(em,1e-10f))));
  }
  float t = __fmul_rn(__fmul_rn(nep,1024.0f),10.0f);
  t = __fdiv_rn(-t, 0.01f);
  t = __fsub_rn(t, 0.001f);
  float dec = expf(t);
  float onem = __fsub_rn(1.0f, dec);
  int a = anchor[n];
  float nv = __fadd_rn(__fmul_rn(emb[(size_t)n*ED+e], onem),
                       __fmul_rn(z[(size_t)a*ED+e], dec));
  out[OFF_NEMB + (size_t)n*ED + e] = nv;
}

__global__ void finalize_kernel(const double* __restrict__ accs, float* __restrict__ out){
  if (threadIdx.x==0 && blockIdx.x==0){
    float l1 = (float)(accs[0] / 4194304.0);
    float contra = (float)(accs[1] / 1024.0);
    out[OFF_LOSS1]=l1; out[OFF_LOSS2]=l1;
    float loss = __fadd_rn(__fadd_rn(__fmul_rn(1.0f,l1), __fmul_rn(0.25f,l1)), contra);
    out[OFF_LOSS]=loss;
    out[OFF_PERP]=expf(-(float)accs[2]);
  }
}

extern "C" void kernel_launch(void* const* d_in, const int* in_sizes, int n_in,
                              void* d_out, int out_size, void* d_ws, size_t ws_size,
                              hipStream_t stream){
  (void)in_sizes; (void)n_in; (void)out_size; (void)ws_size;
  const float* z    = (const float*)d_in[0];
  const float* emb  = (const float*)d_in[1];
  const float* eprb = (const float*)d_in[2];
  float* out = (float*)d_out;
  char* ws = (char*)d_ws;
  double* accs = (double*)ws;                 // [0]=lossSum [1]=contraSum [2]=perpSum
  int* counts = (int*)(ws + 64);              // 1024 ints
  int* anchor = (int*)(ws + 8192);            // 1024 ints
  int* idxw   = (int*)(ws + 16384);           // 65536 ints
  float* cn = out + OFF_IDX;                  // scratch: idx region (written later)
  float* zn = out + OFF_ZOUT;                 // scratch: z_output region (written later)
  float* dT = out + OFF_MINENC;               // scratch: min_encodings region (overwritten later)

  hipMemsetAsync(ws, 0, 16384, stream);
  hipLaunchKernelGGL(norm_emb_kernel, dim3(4), dim3(256), 0, stream, emb, cn);
  hipLaunchKernelGGL(norm_z_kernel, dim3(256), dim3(256), 0, stream, z, zn);
  hipLaunchKernelGGL(gemm_kernel, dim3(4096), dim3(256), 0, stream, zn, cn, dT, idxw, counts);
  hipLaunchKernelGGL(colstats_kernel, dim3(1024), dim3(1024), 0, stream, dT, anchor, accs);
  hipLaunchKernelGGL(scatter_kernel, dim3(256), dim3(256), 0, stream, idxw, dT);
  hipLaunchKernelGGL(zq_kernel, dim3(4096), dim3(256), 0, stream, z, emb, idxw, out, accs);
  hipLaunchKernelGGL(codebook_kernel, dim3(1024), dim3(64), 0, stream, emb, eprb, z, counts, anchor, out, accs+2);
  hipLaunchKernelGGL(finalize_kernel, dim3(1), dim3(1), 0, stream, accs, out);
}

// Round 3
// 515.689 us; speedup vs baseline: 2.3482x; 1.5813x over previous
//
#include <hip/hip_runtime.h>
#include <math.h>

#define NF 65536
#define NE 1024
#define ED 64
#define KBOT 32768
#define RTOP 65472            // NF - 64
#define BINS 2048
#define CAPB 2048
#define CAPT 1024

static const long long OFF_LOSS   = 0;
static const long long OFF_LOSS1  = 1;
static const long long OFF_LOSS2  = 2;
static const long long OFF_ZQST   = 3;
static const long long OFF_ZOUT   = 3LL + 4194304LL;       // 4194307
static const long long OFF_PERP   = 3LL + 8388608LL;       // 8388611
static const long long OFF_MINENC = 8388612LL;             // 16B aligned (x4)
static const long long OFF_IDX    = 75497476LL;            // 16B aligned (x4)
static const long long OFF_NEP    = 75563012LL;
static const long long OFF_NEMB   = 75564036LL;
// scratch placement inside out:
//   cn      = out + OFF_IDX          (256KB, 16B aligned; overwritten by idx output in zq)
//   zn      = out + OFF_ZOUT + 1     (16MB, 16B aligned; overwritten by z_output in zq;
//                                     last float spills into OFF_PERP slot, rewritten by finalize)
//   rowkey8 = out + 4                (512KB u64, 16B aligned; in z_q_st region, overwritten by zq)
//   dT      = out + OFF_MINENC       (268MB; zeroed by colstats -> becomes min_encodings)

__device__ __forceinline__ unsigned ordf(float v){
  unsigned u = __float_as_uint(v);
  return (u & 0x80000000u) ? ~u : (u | 0x80000000u);
}

// Replicates np.linalg.norm(x) for a 64-elem row: squares rounded to fp32,
// pairwise_sum with 8 accumulators + combine tree, sqrt, max(.,1e-12).
__device__ __forceinline__ float np_l2norm_row(const float* __restrict__ x){
  float r[8];
  #pragma unroll
  for (int j=0;j<8;j++){ float t=x[j]; r[j]=__fmul_rn(t,t); }
  #pragma unroll
  for (int b=1;b<8;b++){
    #pragma unroll
    for (int j=0;j<8;j++){ float t=x[b*8+j]; r[j]=__fadd_rn(r[j], __fmul_rn(t,t)); }
  }
  float s = __fadd_rn(__fadd_rn(__fadd_rn(r[0],r[1]),__fadd_rn(r[2],r[3])),
                      __fadd_rn(__fadd_rn(r[4],r[5]),__fadd_rn(r[6],r[7])));
  float nr = __fsqrt_rn(s);
  return fmaxf(nr, 1e-12f);
}

__global__ void norm_z_kernel(const float* __restrict__ z, float* __restrict__ zn){
  int f = blockIdx.x*blockDim.x + threadIdx.x;    // < 65536
  const float* x = z + (size_t)f*ED;
  float nr = np_l2norm_row(x);
  float* o = zn + (size_t)f*ED;
  #pragma unroll
  for (int i=0;i<ED;i++) o[i] = __fdiv_rn(x[i], nr);
}

__global__ void norm_emb_kernel(const float* __restrict__ emb, float* __restrict__ cn){
  int n = blockIdx.x*blockDim.x + threadIdx.x;    // < 1024
  const float* x = emb + (size_t)n*ED;
  float nr = np_l2norm_row(x);
  float* o = cn + (size_t)n*ED;
  #pragma unroll
  for (int i=0;i<ED;i++) o[i] = __fdiv_rn(x[i], nr);
}

// d = zn @ cn^T (65536x1024, K=64) stored transposed dT[c][r].
// LDS-tiled 128x128, 8x8 register blocking, XOR-swizzled LDS (linear dest,
// pre-swizzled source index). Per-row best key over this block's 128 cols
// written to rowkey8[row][cblk] (deterministic, no atomics).
__global__ __launch_bounds__(256) void gemm_kernel(const float* __restrict__ zn,
      const float* __restrict__ cn, float* __restrict__ dT,
      unsigned long long* __restrict__ rowkey8){
  __shared__ float4 zsh[128*16];   // [r][slot], slot = q ^ ((r>>3)&7)
  __shared__ float4 wsh[128*16];   // [c][slot], slot = q ^ (c&7)
  const int tid = threadIdx.x;
  const int rblk = blockIdx.x >> 3;          // 0..511
  const int cblk = blockIdx.x & 7;           // 0..7
  const int r0 = rblk*128, c0g = cblk*128;

  const float4* zg = (const float4*)(zn + (size_t)r0*ED);
  const float4* wg = (const float4*)(cn + (size_t)c0g*ED);
  #pragma unroll
  for (int i=0;i<8;i++){
    int di = i*256 + tid;                    // float4 slot 0..2047
    int c = di>>4, q = di&15;
    wsh[di] = wg[c*16 + (q ^ (c&7))];
    zsh[di] = zg[c*16 + (q ^ ((c>>3)&7))];   // c doubles as row index here
  }
  __syncthreads();

  const int l  = tid & 63;
  const int wv = tid >> 6;
  const int rg = l >> 4;                     // 0..3
  const int cl = l & 15;                     // 0..15
  const int rowb = wv*32 + rg*8;             // lane's 8 consecutive local rows
  const int zsw = ((rowb>>3)&7);             // z swizzle for this lane's rows (r>>3 = rowb>>3, const over r? no)
  const int sw = cl & 7;                     // w swizzle (c&7 == cl&7 for c=cl+16j)

  float acc[8][8];
  #pragma unroll
  for (int r=0;r<8;r++)
    #pragma unroll
    for (int j=0;j<8;j++) acc[r][j]=0.0f;

  for (int q=0;q<16;q++){
    float4 zv[8], wvv[8];
    #pragma unroll
    for (int r=0;r<8;r++){
      int row = rowb + r;                    // rows rowb..rowb+7, all same (row>>3)
      zv[r] = zsh[row*16 + (q ^ zsw)];
    }
    #pragma unroll
    for (int j=0;j<8;j++){
      int c = cl + 16*j;
      wvv[j] = wsh[c*16 + (q ^ sw)];
    }
    #pragma unroll
    for (int r=0;r<8;r++){
      #pragma unroll
      for (int j=0;j<8;j++){
        float a = acc[r][j];
        a = fmaf(zv[r].x, wvv[j].x, a);
        a = fmaf(zv[r].y, wvv[j].y, a);
        a = fmaf(zv[r].z, wvv[j].z, a);
        a = fmaf(zv[r].w, wvv[j].w, a);
        acc[r][j] = a;
      }
    }
  }

  // store dT[c][r0+rowb .. +8] as two float4 per column
  #pragma unroll
  for (int j=0;j<8;j++){
    int col = c0g + cl + 16*j;
    float4* dst = (float4*)(dT + (size_t)col*NF + r0 + rowb);
    dst[0] = make_float4(acc[0][j],acc[1][j],acc[2][j],acc[3][j]);
    dst[1] = make_float4(acc[4][j],acc[5][j],acc[6][j],acc[7][j]);
  }

  // per-row argmax over this block's 128 columns
  #pragma unroll
  for (int r=0;r<8;r++){
    float bv = acc[r][0]; int bc = c0g + cl;
    #pragma unroll
    for (int j=1;j<8;j++){
      int c = c0g + cl + 16*j;
      if (acc[r][j] > bv){ bv = acc[r][j]; bc = c; }
    }
    unsigned long long key = ((unsigned long long)ordf(bv)<<32) |
                             (unsigned long long)(0xFFFFFFFFu - (unsigned)bc);
    #pragma unroll
    for (int m=1;m<16;m<<=1){
      unsigned long long o = __shfl_xor(key, m);
      if (o > key) key = o;
    }
    if (cl==0) rowkey8[(size_t)(r0 + rowb + r)*8 + cblk] = key;
  }
}

__global__ void idx_kernel(const unsigned long long* __restrict__ rowkey8,
                           int* __restrict__ idxw, int* __restrict__ counts){
  int f = blockIdx.x*256 + threadIdx.x;     // < 65536
  unsigned long long K = rowkey8[(size_t)f*8];
  #pragma unroll
  for (int w=1;w<8;w++){
    unsigned long long o = rowkey8[(size_t)f*8 + w];
    if (o > K) K = o;
  }
  int col = (int)(0xFFFFFFFFu - (unsigned)(K & 0xFFFFFFFFull));
  idxw[f] = col;
  atomicAdd(&counts[col], 1);
}

__device__ void bitonic_sort(float* buf, int N, int tid, int nthr){
  for (int k=2;k<=N;k<<=1){
    for (int j=k>>1;j>0;j>>=1){
      for (int t=tid;t<N;t+=nthr){
        int ixj = t ^ j;
        if (ixj > t){
          float a = buf[t], b = buf[ixj];
          bool up = ((t & k) == 0);
          bool sw = up ? (a > b) : (a < b);
          if (sw){ buf[t]=b; buf[ixj]=a; }
        }
      }
      __syncthreads();
    }
  }
}

// One block (1024 thr) per codebook column: histogram selection + exact
// top-64 mean and exact bottom-32768 exp-sum; zero-writes its slice after.
__global__ __launch_bounds__(1024) void colstats_kernel(float* __restrict__ dT,
        int* __restrict__ anchor, double* __restrict__ accs){
  __shared__ unsigned hist[BINS];
  __shared__ unsigned scan[1024];
  __shared__ float bufB[CAPB];
  __shared__ float bufT[CAPT];
  __shared__ float redf[1024];
  __shared__ unsigned long long redk[16];
  __shared__ float s_m0f;
  __shared__ int s_anch;
  __shared__ int s_binB, s_cbelow, s_binT;
  __shared__ int s_cntB, s_cntT;

  const int tid = threadIdx.x;
  const int n = blockIdx.x;
  float* __restrict__ p = dT + (size_t)n*NF;

  hist[tid]=0u; hist[tid+1024]=0u;
  if (tid==0){ s_cntB=0; s_cntT=0; }
  __syncthreads();

  unsigned long long bk=0ull;
  for (int i=tid;i<NF;i+=1024){
    float v = p[i];
    unsigned long long key = ((unsigned long long)ordf(v)<<32) |
                             (unsigned long long)(~(unsigned)i);
    if (key>bk) bk=key;
    int b = (int)((v+1.0f)*1024.0f);
    b = b<0?0:(b>BINS-1?BINS-1:b);
    atomicAdd(&hist[b],1u);
  }
  #pragma unroll
  for (int off=32;off;off>>=1){
    unsigned long long o=__shfl_down(bk,off);
    if (o>bk) bk=o;
  }
  if ((tid&63)==0) redk[tid>>6]=bk;
  __syncthreads();
  if (tid==0){
    unsigned long long K=redk[0];
    #pragma unroll
    for (int w=1;w<16;w++) if (redk[w]>K) K=redk[w];
    unsigned ou=(unsigned)(K>>32);
    unsigned u = (ou&0x80000000u)?(ou^0x80000000u):~ou;
    s_m0f = __uint_as_float(u);
    s_anch = (int)(~(unsigned)(K&0xFFFFFFFFull));
  }

  const unsigned h0 = hist[2*tid], h1 = hist[2*tid+1];
  const unsigned c2 = h0+h1;
  scan[tid]=c2;
  __syncthreads();
  for (int off=1;off<1024;off<<=1){
    unsigned y = (tid>=off)? scan[tid-off] : 0u;
    __syncthreads();
    scan[tid]+=y;
    __syncthreads();
  }
  {
    const unsigned inc = scan[tid];
    const unsigned pre = inc - c2;
    if (pre < (unsigned)KBOT && pre+h0 >= (unsigned)KBOT){ s_binB=2*tid;   s_cbelow=(int)pre; }
    else if (pre+h0 < (unsigned)KBOT && inc >= (unsigned)KBOT){ s_binB=2*tid+1; s_cbelow=(int)(pre+h0); }
    if (pre <= (unsigned)RTOP && (unsigned)RTOP < pre+h0) s_binT=2*tid;
    else if (pre+h0 <= (unsigned)RTOP && (unsigned)RTOP < inc) s_binT=2*tid+1;
  }
  __syncthreads();

  const int binB=s_binB, binT=s_binT;
  const float m0=s_m0f;
  const float LINV = 1.0f/0.07f;
  float es=0.0f;
  for (int i=tid;i<NF;i+=1024){
    float v=p[i];
    int b=(int)((v+1.0f)*1024.0f);
    b=b<0?0:(b>BINS-1?BINS-1:b);
    if (b<binB) es += expf((v-m0)*LINV);
    if (b==binB){ int pos=atomicAdd(&s_cntB,1); if (pos<CAPB) bufB[pos]=v; }
    if (b>=binT){ int pos=atomicAdd(&s_cntT,1); if (pos<CAPT) bufT[pos]=v; }
  }
  redf[tid]=es;
  __syncthreads();
  for (int off=512;off;off>>=1){
    if (tid<off) redf[tid]+=redf[tid+off];
    __syncthreads();
  }
  const float E_below = redf[0];
  const int cntB = (s_cntB<CAPB)?s_cntB:CAPB;
  const int cntT = (s_cntT<CAPT)?s_cntT:CAPT;
  __syncthreads();
  for (int i=cntB+tid;i<CAPB;i+=1024) bufB[i]=__uint_as_float(0x7f800000u);
  for (int i=cntT+tid;i<CAPT;i+=1024) bufT[i]=__uint_as_float(0xff800000u);
  __syncthreads();
  bitonic_sort(bufB, CAPB, tid, 1024);
  bitonic_sort(bufT, CAPT, tid, 1024);
  int m = KBOT - s_cbelow; if (m>cntB) m=cntB;
  float es2=0.0f;
  for (int i=tid;i<m;i+=1024) es2 += expf((bufB[i]-m0)*LINV);
  redf[tid]=es2;
  __syncthreads();
  for (int off=512;off;off>>=1){ if (tid<off) redf[tid]+=redf[tid+off]; __syncthreads(); }
  const float E_bin = redf[0];
  __syncthreads();
  redf[tid] = (tid<64) ? bufT[CAPT-64+tid] : 0.0f;
  __syncthreads();
  for (int off=512;off;off>>=1){ if (tid<off) redf[tid]+=redf[tid+off]; __syncthreads(); }
  if (tid==0){
    float topSum = redf[0];
    float dis_pos = topSum*(1.0f/64.0f);
    float S = (E_below+E_bin)*expf((m0-dis_pos)*LINV);
    atomicAdd(&accs[1], (double)log1pf(S));
    anchor[n] = s_anch;
  }
  float4 z4 = make_float4(0.f,0.f,0.f,0.f);
  float4* p4 = (float4*)p;
  for (int i=tid;i<NF/4;i+=1024) p4[i]=z4;
}

__global__ void scatter_kernel(const int* __restrict__ idxw, float* __restrict__ minenc){
  int f = blockIdx.x*256 + threadIdx.x;
  minenc[(size_t)f*NE + idxw[f]] = 1.0f;
}

__global__ __launch_bounds__(256) void zq_kernel(const float* __restrict__ z,
        const float* __restrict__ emb, const int* __restrict__ idxw,
        float* __restrict__ out, double* __restrict__ lossAcc){
  const int gid = blockIdx.x*256 + threadIdx.x;   // < 1048576 (float4 units)
  const int f = gid >> 4;
  const int e0 = (gid & 15)*4;
  const int c = idxw[f];
  const float4 q = *(const float4*)(emb + (size_t)c*ED + e0);
  const float4 zv = ((const float4*)z)[gid];
  float dx=__fsub_rn(q.x,zv.x), dy=__fsub_rn(q.y,zv.y);
  float dz2=__fsub_rn(q.z,zv.z), dw=__fsub_rn(q.w,zv.w);
  float ox=__fadd_rn(zv.x,dx), oy=__fadd_rn(zv.y,dy);
  float oz=__fadd_rn(zv.z,dz2), ow=__fadd_rn(zv.w,dw);
  size_t base = (size_t)gid*4;
  float* zq = out + OFF_ZQST; float* zo = out + OFF_ZOUT;
  zq[base+0]=ox; zq[base+1]=oy; zq[base+2]=oz; zq[base+3]=ow;
  zo[base+0]=ox; zo[base+1]=oy; zo[base+2]=oz; zo[base+3]=ow;
  if ((gid&15)==0) out[OFF_IDX + f] = (float)c;
  float ls = __fadd_rn(__fadd_rn(__fmul_rn(dx,dx),__fmul_rn(dy,dy)),
                       __fadd_rn(__fmul_rn(dz2,dz2),__fmul_rn(dw,dw)));
  #pragma unroll
  for (int off=32;off;off>>=1) ls += __shfl_down(ls, off);
  __shared__ float rw[4];
  if ((threadIdx.x&63)==0) rw[threadIdx.x>>6]=ls;
  __syncthreads();
  if (threadIdx.x==0) atomicAdd(lossAcc, (double)(((rw[0]+rw[1])+(rw[2]+rw[3]))));
}

__global__ void codebook_kernel(const float* __restrict__ emb, const float* __restrict__ eprob,
     const float* __restrict__ z, const int* __restrict__ counts, const int* __restrict__ anchor,
     float* __restrict__ out, double* __restrict__ perpAcc){
  const int n = blockIdx.x;
  const int e = threadIdx.x;   // 64
  float em = (float)counts[n] * (1.0f/65536.0f);
  float nep = __fadd_rn(__fmul_rn(eprob[n],0.99f), __fmul_rn(em,0.01f));
  if (e==0){
    out[OFF_NEP + n] = nep;
    atomicAdd(perpAcc, (double)__fmul_rn(em, logf(__fadd_rn(em,1e-10f))));
  }
  float t = __fmul_rn(__fmul_rn(nep,1024.0f),10.0f);
  t = __fdiv_rn(-t, 0.01f);
  t = __fsub_rn(t, 0.001f);
  float dec = expf(t);
  float onem = __fsub_rn(1.0f, dec);
  int a = anchor[n];
  float nv = __fadd_rn(__fmul_rn(emb[(size_t)n*ED+e], onem),
                       __fmul_rn(z[(size_t)a*ED+e], dec));
  out[OFF_NEMB + (size_t)n*ED + e] = nv;
}

__global__ void finalize_kernel(const double* __restrict__ accs, float* __restrict__ out){
  if (threadIdx.x==0 && blockIdx.x==0){
    float l1 = (float)(accs[0] / 4194304.0);
    float contra = (float)(accs[1] / 1024.0);
    out[OFF_LOSS1]=l1; out[OFF_LOSS2]=l1;
    float loss = __fadd_rn(__fadd_rn(__fmul_rn(1.0f,l1), __fmul_rn(0.25f,l1)), contra);
    out[OFF_LOSS]=loss;
    out[OFF_PERP]=expf(-(float)accs[2]);
  }
}

extern "C" void kernel_launch(void* const* d_in, const int* in_sizes, int n_in,
                              void* d_out, int out_size, void* d_ws, size_t ws_size,
                              hipStream_t stream){
  (void)in_sizes; (void)n_in; (void)out_size; (void)ws_size;
  const float* z    = (const float*)d_in[0];
  const float* emb  = (const float*)d_in[1];
  const float* eprb = (const float*)d_in[2];
  float* out = (float*)d_out;
  char* ws = (char*)d_ws;
  double* accs = (double*)ws;                 // [0]=lossSum [1]=contraSum [2]=perpSum
  int* counts = (int*)(ws + 64);              // 1024 ints
  int* anchor = (int*)(ws + 8192);            // 1024 ints
  int* idxw   = (int*)(ws + 16384);           // 65536 ints
  float* cn = out + OFF_IDX;                  // scratch (overwritten by idx output)
  float* zn = out + OFF_ZOUT + 1;             // scratch, 16B-aligned (overwritten by z_output)
  float* dT = out + OFF_MINENC;               // scratch (becomes min_encodings)
  unsigned long long* rowkey8 = (unsigned long long*)(out + 4);  // in z_q_st region

  hipMemsetAsync(ws, 0, 16384, stream);
  hipLaunchKernelGGL(norm_emb_kernel, dim3(4), dim3(256), 0, stream, emb, cn);
  hipLaunchKernelGGL(norm_z_kernel, dim3(256), dim3(256), 0, stream, z, zn);
  hipLaunchKernelGGL(gemm_kernel, dim3(4096), dim3(256), 0, stream, zn, cn, dT, rowkey8);
  hipLaunchKernelGGL(idx_kernel, dim3(256), dim3(256), 0, stream, rowkey8, idxw, counts);
  hipLaunchKernelGGL(colstats_kernel, dim3(1024), dim3(1024), 0, stream, dT, anchor, accs);
  hipLaunchKernelGGL(scatter_kernel, dim3(256), dim3(256), 0, stream, idxw, dT);
  hipLaunchKernelGGL(zq_kernel, dim3(4096), dim3(256), 0, stream, z, emb, idxw, out, accs);
  hipLaunchKernelGGL(codebook_kernel, dim3(1024), dim3(64), 0, stream, emb, eprb, z, counts, anchor, out, accs+2);
  hipLaunchKernelGGL(finalize_kernel, dim3(1), dim3(1), 0, stream, accs, out);
}

// Round 4
// 400.726 us; speedup vs baseline: 3.0219x; 1.2869x over previous
//
#include <hip/hip_runtime.h>
#include <math.h>

#define NF 65536
#define NE 1024
#define ED 64
#define KBOT 32768
#define RTOP 65472            // NF - 64
#define BINS 2048
#define CAPB 2048
#define CAPT 1024

static const long long OFF_LOSS   = 0;
static const long long OFF_LOSS1  = 1;
static const long long OFF_LOSS2  = 2;
static const long long OFF_ZQST   = 3;
static const long long OFF_ZOUT   = 3LL + 4194304LL;       // 4194307
static const long long OFF_PERP   = 3LL + 8388608LL;       // 8388611
static const long long OFF_MINENC = 8388612LL;             // 16B aligned (x4)
static const long long OFF_IDX    = 75497476LL;            // 16B aligned (x4)
static const long long OFF_NEP    = 75563012LL;
static const long long OFF_NEMB   = 75564036LL;
// scratch placement inside out:
//   cn      = out + OFF_IDX          (256KB; overwritten by idx output in zq)
//   zn      = out + OFF_ZOUT + 1     (16MB, 16B aligned; overwritten by z_output)
//   rowkey8 = out + 4                (4MB u64; in z_q_st region, overwritten by zq)
//   dT      = out + OFF_MINENC       (268MB; zeroed by colstats -> min_encodings)

__device__ __forceinline__ unsigned ordf(float v){
  unsigned u = __float_as_uint(v);
  return (u & 0x80000000u) ? ~u : (u | 0x80000000u);
}

// Replicates np.linalg.norm for a 64-elem row (pairwise-8 order), sqrt, max(,1e-12).
__device__ __forceinline__ float np_l2norm_row(const float* __restrict__ x){
  float r[8];
  #pragma unroll
  for (int j=0;j<8;j++){ float t=x[j]; r[j]=__fmul_rn(t,t); }
  #pragma unroll
  for (int b=1;b<8;b++){
    #pragma unroll
    for (int j=0;j<8;j++){ float t=x[b*8+j]; r[j]=__fadd_rn(r[j], __fmul_rn(t,t)); }
  }
  float s = __fadd_rn(__fadd_rn(__fadd_rn(r[0],r[1]),__fadd_rn(r[2],r[3])),
                      __fadd_rn(__fadd_rn(r[4],r[5]),__fadd_rn(r[6],r[7])));
  float nr = __fsqrt_rn(s);
  return fmaxf(nr, 1e-12f);
}

__global__ void norm_z_kernel(const float* __restrict__ z, float* __restrict__ zn){
  int f = blockIdx.x*blockDim.x + threadIdx.x;    // < 65536
  float xv[ED];
  const float4* xg = (const float4*)(z + (size_t)f*ED);
  #pragma unroll
  for (int i=0;i<16;i++) *(float4*)&xv[i*4] = xg[i];
  float nr = np_l2norm_row(xv);
  float4* o = (float4*)(zn + (size_t)f*ED);
  #pragma unroll
  for (int i=0;i<16;i++){
    float4 v;
    v.x=__fdiv_rn(xv[i*4+0],nr); v.y=__fdiv_rn(xv[i*4+1],nr);
    v.z=__fdiv_rn(xv[i*4+2],nr); v.w=__fdiv_rn(xv[i*4+3],nr);
    o[i]=v;
  }
}

__global__ void norm_emb_kernel(const float* __restrict__ emb, float* __restrict__ cn){
  int n = blockIdx.x*blockDim.x + threadIdx.x;    // < 1024
  float xv[ED];
  const float4* xg = (const float4*)(emb + (size_t)n*ED);
  #pragma unroll
  for (int i=0;i<16;i++) *(float4*)&xv[i*4] = xg[i];
  float nr = np_l2norm_row(xv);
  float4* o = (float4*)(cn + (size_t)n*ED);
  #pragma unroll
  for (int i=0;i<16;i++){
    float4 v;
    v.x=__fdiv_rn(xv[i*4+0],nr); v.y=__fdiv_rn(xv[i*4+1],nr);
    v.z=__fdiv_rn(xv[i*4+2],nr); v.w=__fdiv_rn(xv[i*4+3],nr);
    o[i]=v;
  }
}

// d = zn @ cn^T (65536x1024, K=64) stored transposed dT[c][r].
// LDS-tiled 128x128, 8x8 register blocking, XOR-swizzled LDS.
__global__ __launch_bounds__(256) void gemm_kernel(const float* __restrict__ zn,
      const float* __restrict__ cn, float* __restrict__ dT,
      unsigned long long* __restrict__ rowkey8){
  __shared__ float4 zsh[128*16];   // [r][slot], slot = q ^ ((r>>3)&7)
  __shared__ float4 wsh[128*16];   // [c][slot], slot = q ^ (c&7)
  const int tid = threadIdx.x;
  const int rblk = blockIdx.x >> 3;          // 0..511
  const int cblk = blockIdx.x & 7;           // 0..7
  const int r0 = rblk*128, c0g = cblk*128;

  const float4* zg = (const float4*)(zn + (size_t)r0*ED);
  const float4* wg = (const float4*)(cn + (size_t)c0g*ED);
  #pragma unroll
  for (int i=0;i<8;i++){
    int di = i*256 + tid;                    // float4 slot 0..2047
    int c = di>>4, q = di&15;
    wsh[di] = wg[c*16 + (q ^ (c&7))];
    zsh[di] = zg[c*16 + (q ^ ((c>>3)&7))];   // c doubles as row index here
  }
  __syncthreads();

  const int l  = tid & 63;
  const int wv = tid >> 6;
  const int rg = l >> 4;                     // 0..3
  const int cl = l & 15;                     // 0..15
  const int rowb = wv*32 + rg*8;             // lane's 8 consecutive local rows
  const int zsw = ((rowb>>3)&7);
  const int sw = cl & 7;

  float acc[8][8];
  #pragma unroll
  for (int r=0;r<8;r++)
    #pragma unroll
    for (int j=0;j<8;j++) acc[r][j]=0.0f;

  for (int q=0;q<16;q++){
    float4 zv[8], wvv[8];
    #pragma unroll
    for (int r=0;r<8;r++){
      int row = rowb + r;
      zv[r] = zsh[row*16 + (q ^ zsw)];
    }
    #pragma unroll
    for (int j=0;j<8;j++){
      int c = cl + 16*j;
      wvv[j] = wsh[c*16 + (q ^ sw)];
    }
    #pragma unroll
    for (int r=0;r<8;r++){
      #pragma unroll
      for (int j=0;j<8;j++){
        float a = acc[r][j];
        a = fmaf(zv[r].x, wvv[j].x, a);
        a = fmaf(zv[r].y, wvv[j].y, a);
        a = fmaf(zv[r].z, wvv[j].z, a);
        a = fmaf(zv[r].w, wvv[j].w, a);
        acc[r][j] = a;
      }
    }
  }

  #pragma unroll
  for (int j=0;j<8;j++){
    int col = c0g + cl + 16*j;
    float4* dst = (float4*)(dT + (size_t)col*NF + r0 + rowb);
    dst[0] = make_float4(acc[0][j],acc[1][j],acc[2][j],acc[3][j]);
    dst[1] = make_float4(acc[4][j],acc[5][j],acc[6][j],acc[7][j]);
  }

  #pragma unroll
  for (int r=0;r<8;r++){
    float bv = acc[r][0]; int bc = c0g + cl;
    #pragma unroll
    for (int j=1;j<8;j++){
      int c = c0g + cl + 16*j;
      if (acc[r][j] > bv){ bv = acc[r][j]; bc = c; }
    }
    unsigned long long key = ((unsigned long long)ordf(bv)<<32) |
                             (unsigned long long)(0xFFFFFFFFu - (unsigned)bc);
    #pragma unroll
    for (int m=1;m<16;m<<=1){
      unsigned long long o = __shfl_xor(key, m);
      if (o > key) key = o;
    }
    if (cl==0) rowkey8[(size_t)(r0 + rowb + r)*8 + cblk] = key;
  }
}

__global__ void idx_kernel(const unsigned long long* __restrict__ rowkey8,
                           int* __restrict__ idxw, int* __restrict__ counts){
  int f = blockIdx.x*256 + threadIdx.x;     // < 65536
  unsigned long long K = rowkey8[(size_t)f*8];
  #pragma unroll
  for (int w=1;w<8;w++){
    unsigned long long o = rowkey8[(size_t)f*8 + w];
    if (o > K) K = o;
  }
  int col = (int)(0xFFFFFFFFu - (unsigned)(K & 0xFFFFFFFFull));
  idxw[f] = col;
  atomicAdd(&counts[col], 1);
}

__device__ void bitonic_sort_dyn(float* buf, int N, int tid){
  for (int k=2;k<=N;k<<=1){
    for (int j=k>>1;j>0;j>>=1){
      for (int t=tid;t<N;t+=1024){
        int ixj = t ^ j;
        if (ixj > t){
          float a = buf[t], b = buf[ixj];
          bool up = ((t & k) == 0);
          bool sw = up ? (a > b) : (a < b);
          if (sw){ buf[t]=b; buf[ixj]=a; }
        }
      }
      __syncthreads();
    }
  }
}

// One block (1024 thr) per codebook column: histogram selection + exact
// top-64 mean and exact bottom-32768 exp-sum; zero-writes its slice after.
__global__ __launch_bounds__(1024) void colstats_kernel(float* __restrict__ dT,
        int* __restrict__ anchor, double* __restrict__ accs){
  __shared__ unsigned hist[BINS];
  __shared__ float bufB[CAPB];
  __shared__ float bufT[CAPT];
  __shared__ unsigned wtot[16];
  __shared__ float wred[16];
  __shared__ unsigned long long redk[16];
  __shared__ float s_m0f;
  __shared__ int s_anch;
  __shared__ int s_binB, s_cbelow, s_binT;
  __shared__ int s_cntB, s_cntT;
  __shared__ float s_Ebelow, s_Ebin;

  const int tid = threadIdx.x;
  const int lane = tid & 63;
  const int wid = tid >> 6;           // 0..15
  const int n = blockIdx.x;
  float* __restrict__ p = dT + (size_t)n*NF;
  const float4* __restrict__ p4c = (const float4*)p;

  hist[tid]=0u; hist[tid+1024]=0u;
  if (tid==0){ s_cntB=0; s_cntT=0; }
  __syncthreads();

  // ---- pass 1 (float4): histogram + max-key ----
  unsigned long long bk=0ull;
  for (int i4=tid;i4<NF/4;i4+=1024){
    float4 v4 = p4c[i4];
    int base = i4*4;
    #pragma unroll
    for (int c=0;c<4;c++){
      float v = (c==0)?v4.x:(c==1)?v4.y:(c==2)?v4.z:v4.w;
      unsigned long long key = ((unsigned long long)ordf(v)<<32) |
                               (unsigned long long)(~(unsigned)(base+c));
      if (key>bk) bk=key;
      int b = (int)((v+1.0f)*1024.0f);
      b = b<0?0:(b>BINS-1?BINS-1:b);
      atomicAdd(&hist[b],1u);
    }
  }
  #pragma unroll
  for (int off=32;off;off>>=1){
    unsigned long long o=__shfl_down(bk,off);
    if (o>bk) bk=o;
  }
  if (lane==0) redk[wid]=bk;
  __syncthreads();
  if (tid==0){
    unsigned long long K=redk[0];
    #pragma unroll
    for (int w=1;w<16;w++) if (redk[w]>K) K=redk[w];
    unsigned ou=(unsigned)(K>>32);
    unsigned u = (ou&0x80000000u)?(ou^0x80000000u):~ou;
    s_m0f = __uint_as_float(u);
    s_anch = (int)(~(unsigned)(K&0xFFFFFFFFull));
  }

  // ---- hierarchical inclusive scan over bin-pairs (2 syncs) ----
  const unsigned h0 = hist[2*tid], h1 = hist[2*tid+1];
  const unsigned c2 = h0+h1;
  unsigned x = c2;
  #pragma unroll
  for (int off=1;off<64;off<<=1){
    unsigned y = __shfl_up(x, off);
    if (lane >= off) x += y;
  }
  if (lane==63) wtot[wid] = x;
  __syncthreads();
  if (wid==0 && lane<16){
    unsigned t = wtot[lane];
    #pragma unroll
    for (int off=1;off<16;off<<=1){
      unsigned y = __shfl_up(t, off);
      if (lane >= off) t += y;
    }
    wtot[lane] = t;   // inclusive wave-totals
  }
  __syncthreads();
  const unsigned inc = x + (wid>0 ? wtot[wid-1] : 0u);
  {
    const unsigned pre = inc - c2;
    if (pre < (unsigned)KBOT && pre+h0 >= (unsigned)KBOT){ s_binB=2*tid;   s_cbelow=(int)pre; }
    else if (pre+h0 < (unsigned)KBOT && inc >= (unsigned)KBOT){ s_binB=2*tid+1; s_cbelow=(int)(pre+h0); }
    if (pre <= (unsigned)RTOP && (unsigned)RTOP < pre+h0) s_binT=2*tid;
    else if (pre+h0 <= (unsigned)RTOP && (unsigned)RTOP < inc) s_binT=2*tid+1;
  }
  __syncthreads();

  // ---- pass 2 (float4): exp-sum below binB + candidate gather ----
  const int binB=s_binB, binT=s_binT;
  const float m0=s_m0f;
  const float LINV = 1.0f/0.07f;
  float es=0.0f;
  for (int i4=tid;i4<NF/4;i4+=1024){
    float4 v4 = p4c[i4];
    #pragma unroll
    for (int c=0;c<4;c++){
      float v = (c==0)?v4.x:(c==1)?v4.y:(c==2)?v4.z:v4.w;
      int b=(int)((v+1.0f)*1024.0f);
      b=b<0?0:(b>BINS-1?BINS-1:b);
      if (b<binB) es += expf((v-m0)*LINV);
      if (b==binB){ int pos=atomicAdd(&s_cntB,1); if (pos<CAPB) bufB[pos]=v; }
      if (b>=binT){ int pos=atomicAdd(&s_cntT,1); if (pos<CAPT) bufT[pos]=v; }
    }
  }
  // wave-reduce es (2 syncs)
  #pragma unroll
  for (int off=32;off;off>>=1) es += __shfl_down(es, off);
  if (lane==0) wred[wid]=es;
  __syncthreads();
  if (tid==0){
    float t=wred[0];
    #pragma unroll
    for (int w=1;w<16;w++) t+=wred[w];
    s_Ebelow=t;
  }
  const int cntB = (s_cntB<CAPB)?s_cntB:CAPB;
  const int cntT = (s_cntT<CAPT)?s_cntT:CAPT;
  __syncthreads();

  // adaptive pow2 sort sizes
  int PB=64; while (PB<cntB) PB<<=1;
  int PT=64; while (PT<cntT) PT<<=1;
  for (int i=cntB+tid;i<PB;i+=1024) bufB[i]=__uint_as_float(0x7f800000u);
  for (int i=cntT+tid;i<PT;i+=1024) bufT[i]=__uint_as_float(0xff800000u);
  __syncthreads();
  bitonic_sort_dyn(bufB, PB, tid);
  bitonic_sort_dyn(bufT, PT, tid);

  int m = KBOT - s_cbelow; if (m>cntB) m=cntB;
  float es2=0.0f;
  for (int i=tid;i<m;i+=1024) es2 += expf((bufB[i]-m0)*LINV);
  #pragma unroll
  for (int off=32;off;off>>=1) es2 += __shfl_down(es2, off);
  if (lane==0) wred[wid]=es2;
  __syncthreads();
  if (tid==0){
    float t=wred[0];
    #pragma unroll
    for (int w=1;w<16;w++) t+=wred[w];
    s_Ebin=t;
  }
  __syncthreads();
  if (wid==0){
    float tv = bufT[PT-64+lane];
    #pragma unroll
    for (int off=32;off;off>>=1) tv += __shfl_down(tv, off);
    if (lane==0){
      float dis_pos = tv*(1.0f/64.0f);
      float S = (s_Ebelow+s_Ebin)*expf((m0-dis_pos)*LINV);
      atomicAdd(&accs[1], (double)log1pf(S));
      anchor[n] = s_anch;
    }
  }
  // ---- zero this column slice (becomes min_encodings zeros) ----
  float4 z4 = make_float4(0.f,0.f,0.f,0.f);
  float4* p4 = (float4*)p;
  for (int i=tid;i<NF/4;i+=1024) p4[i]=z4;
}

__global__ void scatter_kernel(const int* __restrict__ idxw, float* __restrict__ minenc){
  int f = blockIdx.x*256 + threadIdx.x;
  minenc[(size_t)f*NE + idxw[f]] = 1.0f;
}

__global__ __launch_bounds__(256) void zq_kernel(const float* __restrict__ z,
        const float* __restrict__ emb, const int* __restrict__ idxw,
        float* __restrict__ out, double* __restrict__ lossAcc){
  const int gid = blockIdx.x*256 + threadIdx.x;   // < 1048576 (float4 units)
  const int f = gid >> 4;
  const int e0 = (gid & 15)*4;
  const int c = idxw[f];
  const float4 q = *(const float4*)(emb + (size_t)c*ED + e0);
  const float4 zv = ((const float4*)z)[gid];
  float dx=__fsub_rn(q.x,zv.x), dy=__fsub_rn(q.y,zv.y);
  float dz2=__fsub_rn(q.z,zv.z), dw=__fsub_rn(q.w,zv.w);
  float ox=__fadd_rn(zv.x,dx), oy=__fadd_rn(zv.y,dy);
  float oz=__fadd_rn(zv.z,dz2), ow=__fadd_rn(zv.w,dw);
  size_t base = (size_t)gid*4;
  float* zq = out + OFF_ZQST; float* zo = out + OFF_ZOUT;
  zq[base+0]=ox; zq[base+1]=oy; zq[base+2]=oz; zq[base+3]=ow;
  zo[base+0]=ox; zo[base+1]=oy; zo[base+2]=oz; zo[base+3]=ow;
  if ((gid&15)==0) out[OFF_IDX + f] = (float)c;
  float ls = __fadd_rn(__fadd_rn(__fmul_rn(dx,dx),__fmul_rn(dy,dy)),
                       __fadd_rn(__fmul_rn(dz2,dz2),__fmul_rn(dw,dw)));
  #pragma unroll
  for (int off=32;off;off>>=1) ls += __shfl_down(ls, off);
  __shared__ float rw[4];
  if ((threadIdx.x&63)==0) rw[threadIdx.x>>6]=ls;
  __syncthreads();
  if (threadIdx.x==0) atomicAdd(lossAcc, (double)(((rw[0]+rw[1])+(rw[2]+rw[3]))));
}

__global__ void codebook_kernel(const float* __restrict__ emb, const float* __restrict__ eprob,
     const float* __restrict__ z, const int* __restrict__ counts, const int* __restrict__ anchor,
     float* __restrict__ out, double* __restrict__ perpAcc){
  const int n = blockIdx.x;
  const int e = threadIdx.x;   // 64
  float em = (float)counts[n] * (1.0f/65536.0f);
  float nep = __fadd_rn(__fmul_rn(eprob[n],0.99f), __fmul_rn(em,0.01f));
  if (e==0){
    out[OFF_NEP + n] = nep;
    atomicAdd(perpAcc, (double)__fmul_rn(em, logf(__fadd_rn(em,1e-10f))));
  }
  float t = __fmul_rn(__fmul_rn(nep,1024.0f),10.0f);
  t = __fdiv_rn(-t, 0.01f);
  t = __fsub_rn(t, 0.001f);
  float dec = expf(t);
  float onem = __fsub_rn(1.0f, dec);
  int a = anchor[n];
  float nv = __fadd_rn(__fmul_rn(emb[(size_t)n*ED+e], onem),
                       __fmul_rn(z[(size_t)a*ED+e], dec));
  out[OFF_NEMB + (size_t)n*ED + e] = nv;
}

__global__ void finalize_kernel(const double* __restrict__ accs, float* __restrict__ out){
  if (threadIdx.x==0 && blockIdx.x==0){
    float l1 = (float)(accs[0] / 4194304.0);
    float contra = (float)(accs[1] / 1024.0);
    out[OFF_LOSS1]=l1; out[OFF_LOSS2]=l1;
    float loss = __fadd_rn(__fadd_rn(__fmul_rn(1.0f,l1), __fmul_rn(0.25f,l1)), contra);
    out[OFF_LOSS]=loss;
    out[OFF_PERP]=expf(-(float)accs[2]);
  }
}

extern "C" void kernel_launch(void* const* d_in, const int* in_sizes, int n_in,
                              void* d_out, int out_size, void* d_ws, size_t ws_size,
                              hipStream_t stream){
  (void)in_sizes; (void)n_in; (void)out_size; (void)ws_size;
  const float* z    = (const float*)d_in[0];
  const float* emb  = (const float*)d_in[1];
  const float* eprb = (const float*)d_in[2];
  float* out = (float*)d_out;
  char* ws = (char*)d_ws;
  double* accs = (double*)ws;                 // [0]=lossSum [1]=contraSum [2]=perpSum
  int* counts = (int*)(ws + 64);              // 1024 ints
  int* anchor = (int*)(ws + 8192);            // 1024 ints
  int* idxw   = (int*)(ws + 16384);           // 65536 ints
  float* cn = out + OFF_IDX;                  // scratch (overwritten by idx output)
  float* zn = out + OFF_ZOUT + 1;             // scratch, 16B-aligned (overwritten by z_output)
  float* dT = out + OFF_MINENC;               // scratch (becomes min_encodings)
  unsigned long long* rowkey8 = (unsigned long long*)(out + 4);  // in z_q_st region

  hipMemsetAsync(ws, 0, 16384, stream);
  hipLaunchKernelGGL(norm_emb_kernel, dim3(4), dim3(256), 0, stream, emb, cn);
  hipLaunchKernelGGL(norm_z_kernel, dim3(256), dim3(256), 0, stream, z, zn);
  hipLaunchKernelGGL(gemm_kernel, dim3(4096), dim3(256), 0, stream, zn, cn, dT, rowkey8);
  hipLaunchKernelGGL(idx_kernel, dim3(256), dim3(256), 0, stream, rowkey8, idxw, counts);
  hipLaunchKernelGGL(colstats_kernel, dim3(1024), dim3(1024), 0, stream, dT, anchor, accs);
  hipLaunchKernelGGL(scatter_kernel, dim3(256), dim3(256), 0, stream, idxw, dT);
  hipLaunchKernelGGL(zq_kernel, dim3(4096), dim3(256), 0, stream, z, emb, idxw, out, accs);
  hipLaunchKernelGGL(codebook_kernel, dim3(1024), dim3(64), 0, stream, emb, eprb, z, counts, anchor, out, accs+2);
  hipLaunchKernelGGL(finalize_kernel, dim3(1), dim3(1), 0, stream, accs, out);
}